// Round 13
// baseline (378.527 us; speedup 1.0000x reference)
//
#include <hip/hip_runtime.h>

typedef unsigned short u16;

// ---------------- problem constants ----------------
constexpr int NN = 20000;   // nodes
constexpr int EE = 320000;  // edges
constexpr int FD = 128;     // input features
constexpr int C0 = 256;     // hidden (mlp)
constexpr int C1 = 512;     // H*C for GAT
constexpr int NG = 128;     // graphs
constexpr int NC = 10;      // classes
constexpr int NBLK = (NN + 255) / 256;  // 79
constexpr int HB  = 320;                // hist/fill blocks
constexpr int EST = HB * 256;           // edge stride (81920); 4 chunks cover EE
constexpr int PSPL = 16;                // pooling slices per graph

// ---------------- workspace layout (bytes) ----------------
constexpr size_t OFF_XB   = 0;                                   // NN*FD bf16 (dead after gemm1)
constexpr size_t OFF_H1   = OFF_XB  + (size_t)NN * FD * 2;       // NN*C0 bf16
constexpr size_t OFF_H2   = OFF_H1  + (size_t)NN * C0 * 2;       // NN*C0 bf16
constexpr size_t OFF_XW   = OFF_H2  + (size_t)NN * C0 * 2;       // NN*C1 bf16 (ROW-major xw)
constexpr size_t OFF_H34  = OFF_XW  + (size_t)NN * C1 * 2;       // NN*C1 bf16 (h3 then h4, row-major)
constexpr size_t OFF_LS   = OFF_H34 + (size_t)NN * C1 * 2;       // NN*2 f32
constexpr size_t OFF_LD   = OFF_LS  + (size_t)NN * 2 * 4;        // NN*2 f32
constexpr size_t OFF_DEG  = OFF_LD  + (size_t)NN * 2 * 4;        // NN i32
constexpr size_t OFF_OFFS = OFF_DEG + (size_t)NN * 4;            // NN+1 i32 (pad 80016)
constexpr size_t OFF_CUR  = OFF_OFFS + 80016;                    // NN i32
constexpr size_t OFF_CSRC = OFF_CUR + (size_t)NN * 4;            // EE u16 (region sized for old i32; half used)
constexpr size_t OFF_GCNT = OFF_CSRC + (size_t)EE * 4;           // NG i32
constexpr size_t OFF_GOFF = OFF_GCNT + 512;                      // NG+1 i32 (pad 768)
constexpr size_t OFF_PART = OFF_GOFF + 768;                      // NBLK i32 (pad 512)
constexpr size_t OFF_PTOT = OFF_PART + 512;                      // 1 i32 (pad 256)
constexpr size_t OFF_Z1   = OFF_PTOT + 256;                      // (legacy)
constexpr size_t OFF_Z2   = OFF_Z1  + (size_t)NG * C1 * 2;
constexpr size_t OFF_ST   = OFF_Z2  + (size_t)NG * C1 * 2;       // S1,T1,S2,T2 (256 f32), S3,T3 (512 f32)
constexpr size_t OFF_W1T  = OFF_ST  + 8192;
constexpr size_t OFF_W2T  = OFF_W1T + (size_t)FD * C0 * 2;
constexpr size_t OFF_G0T  = OFF_W2T + (size_t)C0 * C0 * 2;
constexpr size_t OFF_G1T  = OFF_G0T + (size_t)C0 * C1 * 2;
constexpr size_t OFF_AUX  = OFF_G1T + (size_t)C1 * C1 * 2;
constexpr size_t OFF_FLAG = OFF_AUX  + 0;      // u32
constexpr size_t OFF_A0S  = OFF_AUX  + 256;    // 512 u16
constexpr size_t OFF_A0D  = OFF_AUX  + 1280;
constexpr size_t OFF_A1S  = OFF_AUX  + 2304;
constexpr size_t OFF_A1D  = OFF_AUX  + 3328;
constexpr size_t OFF_GB0  = OFF_AUX  + 4352;   // 512 f32
constexpr size_t OFF_GB1  = OFF_AUX  + 6400;
constexpr size_t OFF_FB1  = OFF_AUX  + 8448;   // 512 f32
constexpr size_t OFF_FB2  = OFF_AUX  + 10496;  // 10 f32 (pad 256)
constexpr size_t OFF_PP   = OFF_AUX  + 11008;  // f32[NG][PSPL][C1] pooling partials (4 MB)
constexpr size_t OFF_DENA = OFF_PP + (size_t)NG * PSPL * C1 * 4; // (legacy, unused)
constexpr size_t OFF_PLS  = OFF_DENA + (size_t)NN * 2 * 4;       // float2[4][NN] logits partials (640 KB)
// end ~= 75.2 MB

// ---------------- helpers ----------------
__device__ inline float bf2f(u16 u) { return __uint_as_float(((unsigned)u) << 16); }
__device__ inline u16 f2bf(float f) {
    unsigned u = __float_as_uint(f);
    unsigned r = u + 0x7fffu + ((u >> 16) & 1u);   // RNE
    return (u16)(r >> 16);
}
// flag-driven load of an external float input (flag=1 -> f32, 0 -> bf16)
__device__ inline float ldf(const void* p, long i, unsigned f) {
    return f ? ((const float*)p)[i] : bf2f(((const u16*)p)[i]);
}
// 2 VALU ops per 32-bit word (low: shl drops high; high: mask)
__device__ inline void unpack8(uint4 r, float* v) {
    v[0] = __uint_as_float(r.x << 16); v[1] = __uint_as_float(r.x & 0xffff0000u);
    v[2] = __uint_as_float(r.y << 16); v[3] = __uint_as_float(r.y & 0xffff0000u);
    v[4] = __uint_as_float(r.z << 16); v[5] = __uint_as_float(r.z & 0xffff0000u);
    v[6] = __uint_as_float(r.w << 16); v[7] = __uint_as_float(r.w & 0xffff0000u);
}

typedef __bf16 bf16x8_t __attribute__((ext_vector_type(8)));
typedef float  f32x4_t  __attribute__((ext_vector_type(4)));

// async 16B global -> LDS (wave-uniform LDS base + lane*16 layout)
__device__ __forceinline__ void gl_lds16(const u16* g, u16* l) {
    __builtin_amdgcn_global_load_lds((const __attribute__((address_space(1))) void*)g,
                                     (__attribute__((address_space(3))) void*)l, 16, 0, 0);
}

// ---------------- dtype detector ----------------
__global__ void detect_dtype(const u16* __restrict__ x, const u16* __restrict__ w,
                             const u16* __restrict__ fw, unsigned* flag) {
    __shared__ int cnt;
    if (threadIdx.x == 0) cnt = 0;
    __syncthreads();
    int c = 0;
    for (int i = threadIdx.x; i < 4096; i += 256) {
        c += (((x[i]  >> 7) & 0xFF) == 0xFF);
        c += (((w[i]  >> 7) & 0xFF) == 0xFF);
        c += (((fw[i] >> 7) & 0xFF) == 0xFF);
    }
    atomicAdd(&cnt, c);
    __syncthreads();
    if (threadIdx.x == 0) *flag = (cnt >= 2) ? 1u : 0u;  // 1 = f32 inputs
}

// ---------------- x -> internal bf16 copy (+ zero deg/gcnt) ----------------
__global__ void cvt_x(const unsigned* __restrict__ flag, const void* __restrict__ xin,
                      u16* __restrict__ XB, int* __restrict__ deg, int* __restrict__ gcnt) {
    int i = blockIdx.x * 256 + threadIdx.x;  // grid covers NN*FD/4 (2500 blocks)
    if (i < NN) deg[i] = 0;
    if (i < NG) gcnt[i] = 0;
    if (*flag) {
        float4 v = ((const float4*)xin)[i];
        ushort4 r;
        r.x = f2bf(v.x); r.y = f2bf(v.y); r.z = f2bf(v.z); r.w = f2bf(v.w);
        ((ushort4*)XB)[i] = r;
    } else {
        ((ushort4*)XB)[i] = ((const ushort4*)xin)[i];
    }
}

// ---------------- fused params prep + LDS-tiled weight transposes (R13) ----------------
// block 0: params (256 threads, two passes over c). blocks 1..120: one 64x64 tile each,
// via LDS tile[64][65] (pad -> 2-way bank aliasing, free): coalesced 128B reads AND writes.
// Replaces the R12 scattered 2-byte transpose writes (2.6M scattered lines).
__global__ __launch_bounds__(256) void prep_trans(const unsigned* __restrict__ flag,
                            const void* g1, const void* b1, const void* m1, const void* v1, const void* lb1,
                            const void* g2, const void* b2, const void* m2, const void* v2, const void* lb2,
                            const void* g3, const void* b3, const void* m3, const void* v3,
                            const void* a0s, const void* a0d, const void* gb0in,
                            const void* a1s, const void* a1d, const void* gb1in,
                            const void* fb1in, const void* fb2in,
                            float* S1, float* T1, float* S2, float* T2, float* S3, float* T3,
                            u16* A0S, u16* A0D, u16* A1S, u16* A1D,
                            float* GB0, float* GB1, float* FB1, float* FB2,
                            const void* w1, const void* w2, const void* g0w, const void* g1w,
                            u16* w1T, u16* w2T, u16* g0T, u16* g1T) {
    unsigned f = *flag;
    if (blockIdx.x == 0) {
        for (int c = threadIdx.x; c < 512; c += 256) {
            if (c < 256) {
                float s = ldf(g1, c, f) / sqrtf(ldf(v1, c, f) + 1e-5f);
                S1[c] = s; T1[c] = s * (ldf(lb1, c, f) - ldf(m1, c, f)) + ldf(b1, c, f);
                float s2 = ldf(g2, c, f) / sqrtf(ldf(v2, c, f) + 1e-5f);
                S2[c] = s2; T2[c] = s2 * (ldf(lb2, c, f) - ldf(m2, c, f)) + ldf(b2, c, f);
            }
            float s3 = ldf(g3, c, f) / sqrtf(ldf(v3, c, f) + 1e-5f);
            S3[c] = s3; T3[c] = ldf(b3, c, f) - ldf(m3, c, f) * s3;
            A0S[c] = f2bf(ldf(a0s, c, f));
            A0D[c] = f2bf(ldf(a0d, c, f));
            A1S[c] = f2bf(ldf(a1s, c, f));
            A1D[c] = f2bf(ldf(a1d, c, f));
            GB0[c] = ldf(gb0in, c, f);
            GB1[c] = ldf(gb1in, c, f);
            FB1[c] = ldf(fb1in, c, f);
            if (c < NC) FB2[c] = ldf(fb2in, c, f);
        }
        return;
    }
    __shared__ u16 tile[64][65];   // +1 pad: write-back reads stride-65 -> 2-way bank (free)
    int b = blockIdx.x - 1;        // 0..119 tiles
    const void* B; u16* BT; int K, N, base;
    if (b < 8)       { B = w1;  BT = w1T; K = FD; N = C0; base = 0;  }
    else if (b < 24) { B = w2;  BT = w2T; K = C0; N = C0; base = 8;  }
    else if (b < 56) { B = g0w; BT = g0T; K = C0; N = C1; base = 24; }
    else             { B = g1w; BT = g1T; K = C1; N = C1; base = 56; }
    int t = b - base;
    int ntn = N >> 6;
    int k0 = (t / ntn) * 64;
    int n0 = (t % ntn) * 64;
    int r = threadIdx.x >> 6;      // 0..3
    int c = threadIdx.x & 63;      // 0..63
#pragma unroll
    for (int i = 0; i < 16; i++) {
        int kk = r * 16 + i;
        size_t idx = (size_t)(k0 + kk) * N + n0 + c;   // coalesced read (consecutive c)
        tile[kk][c] = f ? f2bf(((const float*)B)[idx]) : ((const u16*)B)[idx];
    }
    __syncthreads();
#pragma unroll
    for (int i = 0; i < 16; i++) {
        int nn = r * 16 + i;
        BT[(size_t)(n0 + nn) * K + k0 + c] = tile[c][nn];  // coalesced write (consecutive c=k)
    }
}

// ---------------- CSR build: histograms (pipelined atomics + wave-run gcnt) ----------------
__global__ __launch_bounds__(256) void hist_k(const int* __restrict__ dst, const int* __restrict__ ew,
                                              const int* __restrict__ batch,
                                              int* __restrict__ deg, int* __restrict__ gcnt) {
    int tid = blockIdx.x * 256 + threadIdx.x;
    int lane = threadIdx.x & 63;
#pragma unroll
    for (int j = 0; j < 4; j++) {
        int e = tid + j * EST;
        if (e < EE && ew[e] == 1) atomicAdd(&deg[dst[e]], 1);
    }
    int n = tid;
    if (n < NN) {
        int g = batch[n];
        int pg = __shfl_up(g, 1);
        bool head = (lane == 0) || (pg != g);
        unsigned long long act = __ballot(1);
        unsigned long long hm  = __ballot(head);
        if (head) {
            unsigned long long above = (lane < 63) ? ((hm >> (lane + 1)) << (lane + 1)) : 0ull;
            int limit = 64 - __builtin_clzll(act);           // highest active lane + 1
            int nxt = above ? __builtin_ctzll(above) : limit;
            atomicAdd(&gcnt[g], nxt - lane);
        }
    }
}
// hierarchical scan: (1) per-block local exclusive scan + block totals
__global__ __launch_bounds__(256) void scan_blk(const int* __restrict__ deg, int* __restrict__ off,
                                                int* __restrict__ part) {
    __shared__ int tmp[256];
    int tid = threadIdx.x, i = blockIdx.x * 256 + tid;
    int v = (i < NN) ? deg[i] : 0;
    tmp[tid] = v;
    __syncthreads();
#pragma unroll
    for (int s = 1; s < 256; s <<= 1) {
        int a = (tid >= s) ? tmp[tid - s] : 0;
        __syncthreads();
        if (tid >= s) tmp[tid] += a;
        __syncthreads();
    }
    if (i < NN) off[i] = tmp[tid] - v;   // block-local exclusive
    if (tid == 255) part[blockIdx.x] = tmp[255];
}
// (2) scan the NBLK partials + scan gcnt -> goff (one small block does both)
__global__ __launch_bounds__(128) void scan_small(int* __restrict__ part, int* __restrict__ ptot,
                                                  const int* __restrict__ gcnt, int* __restrict__ goff) {
    __shared__ int tmp[128];
    int tid = threadIdx.x;
    int v = (tid < NBLK) ? part[tid] : 0;
    tmp[tid] = v;
    __syncthreads();
#pragma unroll
    for (int s = 1; s < 128; s <<= 1) {
        int a = (tid >= s) ? tmp[tid - s] : 0;
        __syncthreads();
        if (tid >= s) tmp[tid] += a;
        __syncthreads();
    }
    if (tid < NBLK) part[tid] = tmp[tid] - v;  // exclusive
    if (tid == 127) *ptot = tmp[127];
    __syncthreads();
    int g = gcnt[tid];
    tmp[tid] = g;
    __syncthreads();
#pragma unroll
    for (int s = 1; s < 128; s <<= 1) {
        int a = (tid >= s) ? tmp[tid - s] : 0;
        __syncthreads();
        if (tid >= s) tmp[tid] += a;
        __syncthreads();
    }
    goff[tid] = tmp[tid] - g;
    if (tid == 127) goff[128] = tmp[127];
}
// (3) add block prefix, emit cursor copy and total
__global__ __launch_bounds__(256) void scan_add(int* __restrict__ off, const int* __restrict__ part,
                                                const int* __restrict__ ptot, int* __restrict__ cursor) {
    int tid = threadIdx.x, i = blockIdx.x * 256 + tid;
    if (i < NN) {
        int o = off[i] + part[blockIdx.x];
        off[i] = o;
        cursor[i] = o;
    }
    if (i == 0) off[NN] = *ptot;
}
// fill: 4 independent atomic-return chains per thread; csrc stored u16 (NN < 65536)
__global__ __launch_bounds__(256) void csr_fill(const int* __restrict__ src, const int* __restrict__ dst,
                                                const int* __restrict__ ew,
                                                int* __restrict__ cursor, u16* __restrict__ csrc) {
    int tid = blockIdx.x * 256 + threadIdx.x;
    bool ok[4]; int sv[4]; int p[4];
#pragma unroll
    for (int j = 0; j < 4; j++) {
        int e = tid + j * EST;
        ok[j] = false; sv[j] = 0; p[j] = 0;
        if (e < EE && ew[e] == 1) {
            ok[j] = true;
            sv[j] = src[e];
            p[j] = atomicAdd(&cursor[dst[e]], 1);
        }
    }
#pragma unroll
    for (int j = 0; j < 4; j++) if (ok[j]) csrc[p[j]] = (u16)sv[j];
}

// ---------------- MFMA GEMM (R11-proven): BK=64, XOR-swizzled staging ----------------
// EPI: 0 = raw bf16; 1 = relu(acc*S[col]+T[col]); 3 = raw + logits partials to pls.
template <int EPI>
__global__ __launch_bounds__(256) void gemm_tile(const u16* __restrict__ A, const u16* __restrict__ BT,
                                                 u16* __restrict__ Cm,
                                                 const float* __restrict__ S, const float* __restrict__ T,
                                                 const u16* __restrict__ asrc, const u16* __restrict__ adst,
                                                 float2* __restrict__ pls,
                                                 int M, int N, int K) {
    __shared__ u16 As[128 * 64];   // [row][k] rows of 64, chunk-swizzled
    __shared__ u16 Bs[128 * 64];   // [col][k]
    const int tid  = threadIdx.x;
    const int wave = tid >> 6;
    const int lane = tid & 63;
    const int quad = lane >> 4;
    const int l16  = lane & 15;
    const int wr0  = (wave >> 1) * 64;
    const int wc0  = (wave & 1) * 64;
    const int row0 = blockIdx.x * 128;
    const int col0 = blockIdx.y * 128;

    const int srow = lane >> 3;               // 0..7 row within 8-row segment
    const int sk   = ((lane & 7) ^ srow) * 8; // PRE-SWIZZLED global chunk offset (u16)
    const u16* gaP[4]; const u16* gbP[4]; u16* laP[4]; u16* lbP[4];
#pragma unroll
    for (int i = 0; i < 4; i++) {
        int rl = wave * 32 + i * 8 + srow;
        int gr = row0 + rl; if (gr >= M) gr = M - 1;   // clamp: loads valid, stores guarded
        gaP[i] = A  + (size_t)gr * K + sk;
        gbP[i] = BT + (size_t)(col0 + rl) * K + sk;    // cols always < N by grid construction
        laP[i] = As + (size_t)rl * 64 + (lane & 7) * 8;  // linear LDS: base + lane*16B
        lbP[i] = Bs + (size_t)rl * 64 + (lane & 7) * 8;
    }

    f32x4_t acc[4][4];
#pragma unroll
    for (int r = 0; r < 4; r++)
#pragma unroll
        for (int c = 0; c < 4; c++)
#pragma unroll
            for (int i = 0; i < 4; i++) acc[r][c][i] = 0.f;

    for (int k0 = 0; k0 < K; k0 += 64) {
#pragma unroll
        for (int i = 0; i < 4; i++) {
            gl_lds16(gaP[i] + k0, laP[i]);
            gl_lds16(gbP[i] + k0, lbP[i]);
        }
        __syncthreads();   // drains vmcnt (async LDS writes) + all waves

#pragma unroll
        for (int kk = 0; kk < 2; kk++) {
            bf16x8_t a[4], b[4];
#pragma unroll
            for (int r = 0; r < 4; r++) {
                int rr = wr0 + r * 16 + l16;
                a[r] = *(const bf16x8_t*)(As + (size_t)rr * 64 + (((kk * 4 + quad) ^ (rr & 7)) * 8));
            }
#pragma unroll
            for (int c = 0; c < 4; c++) {
                int cc = wc0 + c * 16 + l16;
                b[c] = *(const bf16x8_t*)(Bs + (size_t)cc * 64 + (((kk * 4 + quad) ^ (cc & 7)) * 8));
            }
#pragma unroll
            for (int r = 0; r < 4; r++)
#pragma unroll
                for (int c = 0; c < 4; c++)
                    acc[r][c] = __builtin_amdgcn_mfma_f32_16x16x32_bf16(a[r], b[c], acc[r][c], 0, 0, 0);
        }
        __syncthreads();   // LDS reads done before next staging overwrites
    }

    // epilogue: store (+ logits partials for EPI==3; reuses As as a [2][128] float2 buffer)
    float2* lred = reinterpret_cast<float2*>(As);
#pragma unroll
    for (int r = 0; r < 4; r++) {
        int rb = row0 + wr0 + r * 16 + quad * 4;
        float ps[4] = {0.f, 0.f, 0.f, 0.f}, pd[4] = {0.f, 0.f, 0.f, 0.f};
#pragma unroll
        for (int c = 0; c < 4; c++) {
            int col = col0 + wc0 + c * 16 + l16;
            float sc = (EPI == 1) ? S[col] : 0.f;
            float sh = (EPI == 1) ? T[col] : 0.f;
            float av_ = 0.f, dv_ = 0.f;
            if (EPI == 3) { av_ = bf2f(asrc[col]); dv_ = bf2f(adst[col]); }
#pragma unroll
            for (int i = 0; i < 4; i++) {
                int row = rb + i;
                float v = acc[r][c][i];
                if (EPI == 1) v = fmaxf(v * sc + sh, 0.f);
                u16 bv = f2bf(v);
                if (row < M) Cm[(size_t)row * N + col] = bv;
                if (EPI == 3) {
                    float vb = bf2f(bv);           // same bf16-rounded value old logits read back
                    ps[i] = fmaf(vb, av_, ps[i]);
                    pd[i] = fmaf(vb, dv_, pd[i]);
                }
            }
        }
        if (EPI == 3) {
#pragma unroll
            for (int i = 0; i < 4; i++) {
#pragma unroll
                for (int m = 1; m <= 8; m <<= 1) {
                    ps[i] += __shfl_xor(ps[i], m);   // within the 16-lane l16 group (same rows)
                    pd[i] += __shfl_xor(pd[i], m);
                }
            }
            if (l16 == 0) {
#pragma unroll
                for (int i = 0; i < 4; i++) {
                    int rl = wr0 + r * 16 + quad * 4 + i;
                    lred[(size_t)(wave & 1) * 128 + rl] = make_float2(ps[i], pd[i]);
                }
            }
        }
    }
    if (EPI == 3) {
        __syncthreads();
        if (tid < 128) {
            int row = row0 + tid;
            if (row < M) {
                float2 a0 = lred[tid], a1 = lred[128 + tid];   // fixed order -> deterministic
                pls[(size_t)blockIdx.y * NN + row] = make_float2(a0.x + a1.x, a0.y + a1.y);
            }
        }
    }
}

// ---------------- combine per-colblock logits partials -> ls, ld (deterministic) ------------
__global__ __launch_bounds__(256) void ls_combine(const float2* __restrict__ pls,
                                                  float* __restrict__ ls, float* __restrict__ ld) {
    int n = blockIdx.x * 256 + threadIdx.x;
    if (n >= NN) return;
#pragma unroll
    for (int h = 0; h < 2; h++) {
        float2 a = pls[(size_t)(2 * h) * NN + n];
        float2 b = pls[(size_t)(2 * h + 1) * NN + n];
        ls[n * 2 + h] = a.x + b.x;
        ld[n * 2 + h] = a.y + b.y;
    }
}

// ---------------- fused GAT softmax + aggregation (R13: online max+den, 2 passes) -----------
// Template HALF in {0,1}: nodes [HALF*10000, HALF*10000+10000), 2500 blocks each.
// pass 1 (online): running max m and rescaled den (den = den*exp(m_old-m_new) + window_sum).
//   The running max ends at the EXACT max -> pass-2 p = exp(v - mhat) is bit-identical to
//   the previous 3-pass version; den reassociates at ulp level (R4/R8/R10 precedent).
// pass 2: weighted row gather with p recomputed inline.
__device__ __forceinline__ void proc_edge(uint4 c, float w, float* acc) {
    float x[8];
    unpack8(c, x);
#pragma unroll
    for (int q = 0; q < 8; q++) acc[q] = fmaf(w, x[q], acc[q]);
}

template <int HALF>
__global__ __launch_bounds__(256) void gat_agg_fused(const int* __restrict__ off, const u16* __restrict__ csrc,
                                                     const float* __restrict__ ls, const float* __restrict__ ld,
                                                     const u16* __restrict__ xw,
                                                     const float* __restrict__ bias, u16* __restrict__ outh) {
    int n = HALF * (NN / 2) + blockIdx.x * 4 + (threadIdx.x >> 6);   // grid (NN/2)/4 = 2500
    const int lane = threadIdx.x & 63;
    const int h    = lane >> 5;
    const int el   = lane & 31;
    const int hoff = h << 5;
    int beg = off[n], end = off[n + 1];
    float2 ldv = ((const float2*)ld)[n];
    float ldh = h ? ldv.y : ldv.x;

    // pass 1: online max + rescaled den
    float m = -1e30f, den = 0.f;
    for (int base = beg; base < end; base += 32) {
        int e = base + el;
        int ec = e < end ? e : end - 1;      // clamp: loads stay valid
        int sv = csrc[ec];
        float vv = ls[sv * 2 + h] + ldh;
        vv = vv > 0.f ? vv : 0.2f * vv;
        float vm = (e < end) ? vv : -1e30f;
#pragma unroll
        for (int mm = 16; mm >= 1; mm >>= 1) vm = fmaxf(vm, __shfl_xor(vm, mm));  // window max
        float mn = fmaxf(m, vm);
        float p = (e < end) ? __expf(vv - mn) : 0.f;
#pragma unroll
        for (int mm = 16; mm >= 1; mm >>= 1) p += __shfl_xor(p, mm);              // window sum
        den = den * __expf(m - mn) + p;
        m = mn;
    }
    const float mhat = m;   // exact per-node max (fmaxf chain)

    // pass 2: weighted row gather (p recomputed inline, bit-identical vs 3-pass)
    float acc[8];
#pragma unroll
    for (int q = 0; q < 8; q++) acc[q] = 0.f;

#define ROWLD(S) (((const uint4*)(xw + (size_t)(S) * C1))[lane])

    for (int base = beg; base < end; base += 32) {
        int cnt = end - base; if (cnt > 32) cnt = 32;
        int e = base + el;
        int ec = e < end ? e : end - 1;      // clamp: loads stay valid
        int sv = csrc[ec];                   // 32 edge srcs (both halves load same -> broadcast)
        float vv = ls[sv * 2 + h] + ldh;
        vv = vv > 0.f ? vv : 0.2f * vv;
        float myp = __expf(vv - mhat);       // raw p for edge (base+el), my head

        // 4-deep row pipeline
        uint4 r0 = ROWLD(__shfl(sv, 0));
        uint4 r1 = ROWLD(__shfl(sv, 1));
        uint4 r2 = ROWLD(__shfl(sv, 2));
        uint4 r3 = ROWLD(__shfl(sv, 3));

        for (int j = 0; j < cnt; j += 4) {
            uint4 c0 = r0, c1 = r1, c2 = r2, c3 = r3;
            float w0 = __shfl(myp, j + hoff);
            float w1 = __shfl(myp, j + 1 + hoff);  // out-of-range j -> unused (guarded)
            float w2 = __shfl(myp, j + 2 + hoff);
            float w3 = __shfl(myp, j + 3 + hoff);
            if (j + 4 < cnt) {                     // prefetch next 4 rows (clamped -> valid)
                r0 = ROWLD(__shfl(sv, j + 4));
                r1 = ROWLD(__shfl(sv, j + 5));
                r2 = ROWLD(__shfl(sv, j + 6));
                r3 = ROWLD(__shfl(sv, j + 7));
            }
            proc_edge(c0, w0, acc);
            if (j + 1 < cnt) proc_edge(c1, w1, acc);
            if (j + 2 < cnt) proc_edge(c2, w2, acc);
            if (j + 3 < cnt) proc_edge(c3, w3, acc);
        }
    }
#undef ROWLD

    float inv = 1.f / fmaxf(den, 1e-30f);
    int cb = lane * 8;
    const float4* bp = (const float4*)(bias + cb);
    float4 b0 = bp[0], b1 = bp[1];
    uint4 st;
    st.x = (unsigned)f2bf(fmaf(acc[0], inv, b0.x)) | ((unsigned)f2bf(fmaf(acc[1], inv, b0.y)) << 16);
    st.y = (unsigned)f2bf(fmaf(acc[2], inv, b0.z)) | ((unsigned)f2bf(fmaf(acc[3], inv, b0.w)) << 16);
    st.z = (unsigned)f2bf(fmaf(acc[4], inv, b1.x)) | ((unsigned)f2bf(fmaf(acc[5], inv, b1.y)) << 16);
    st.w = (unsigned)f2bf(fmaf(acc[6], inv, b1.z)) | ((unsigned)f2bf(fmaf(acc[7], inv, b1.w)) << 16);
    ((uint4*)(outh + (size_t)n * C1 + cb))[0] = st;
}

// ---------------- two-stage pooling stage 1 (R9-proven) ----------------
__global__ __launch_bounds__(128) void pool_part(const u16* __restrict__ h4, const int* __restrict__ goff,
                                                 float* __restrict__ pp) {
    int g = blockIdx.x, s = blockIdx.y, t = threadIdx.x;
    int b = goff[g], e = goff[g + 1];
    int len = e - b;
    int chunk = (len + PSPL - 1) / PSPL;
    int n0 = b + s * chunk;
    int n1 = n0 + chunk; if (n1 > e) n1 = e;
    float s0 = 0.f, s1 = 0.f, s2 = 0.f, s3 = 0.f;
    for (int n = n0; n < n1; n++) {
        ushort4 v = *(const ushort4*)(h4 + (size_t)n * C1 + t * 4);
        s0 += bf2f(v.x); s1 += bf2f(v.y); s2 += bf2f(v.z); s3 += bf2f(v.w);
    }
    float4* dst = (float4*)(pp + ((size_t)g * PSPL + s) * C1 + t * 4);
    *dst = make_float4(s0, s1, s2, s3);
}

// ---------------- fused pool_fin + BN3 + ReLU + fc1 + fc2 (R10-proven) ----------------
__global__ __launch_bounds__(512) void head_all(const unsigned* __restrict__ flag,
                                                const float* __restrict__ pp, const int* __restrict__ goff,
                                                const float* __restrict__ S3, const float* __restrict__ T3,
                                                const void* __restrict__ w1, const float* __restrict__ FB1,
                                                const void* __restrict__ w2, const float* __restrict__ FB2,
                                                void* __restrict__ out) {
    __shared__ float zrow[512];
    __shared__ float z2row[512];
    __shared__ float red[512];
    int g = blockIdx.x, t = threadIdx.x;
    unsigned f = *flag;
    float s = 0.f;
#pragma unroll
    for (int k = 0; k < PSPL; k++) s += pp[((size_t)g * PSPL + k) * C1 + t];
    int b = goff[g], e = goff[g + 1];
    float mean = s / fmaxf((float)(e - b), 1.f);
    float v = fmaxf(mean * S3[t] + T3[t], 0.f);
    zrow[t] = bf2f(f2bf(v));                  // round through bf16 (old z1 path)
    __syncthreads();
    float acc = 0.f;
    if (f) {
        const float* w = (const float*)w1;
        for (int k = 0; k < 512; k++) acc = fmaf(zrow[k], w[(size_t)k * 512 + t], acc);
    } else {
        const u16* w = (const u16*)w1;
        for (int k = 0; k < 512; k++) acc = fmaf(zrow[k], bf2f(w[(size_t)k * 512 + t]), acc);
    }
    acc += FB1[t];
    z2row[t] = bf2f(f2bf(fmaxf(acc, 0.f)));   // round through bf16 (old z2 path)
    __syncthreads();
    float z2t = z2row[t];
    for (int o = 0; o < NC; o++) {
        float p = f ? z2t * ((const float*)w2)[(size_t)t * NC + o]
                    : z2t * bf2f(((const u16*)w2)[(size_t)t * NC + o]);
        red[t] = p;
        __syncthreads();
#pragma unroll
        for (int sd = 256; sd >= 1; sd >>= 1) {
            if (t < sd) red[t] += red[t + sd];
            __syncthreads();
        }
        if (t == 0) {
            float vv = red[0] + FB2[o];
            if (f) ((float*)out)[g * NC + o] = vv;
            else   ((u16*)out)[g * NC + o] = f2bf(vv);
        }
        __syncthreads();   // red reused next o
    }
}

// ---------------- launch ----------------
extern "C" void kernel_launch(void* const* d_in, const int* in_sizes, int n_in,
                              void* d_out, int out_size, void* d_ws, size_t ws_size,
                              hipStream_t stream) {
    (void)in_sizes; (void)n_in; (void)out_size; (void)ws_size;

    const void* x      = d_in[0];
    const int* ei      = (const int*)d_in[1];
    const int* src     = ei;
    const int* dst     = ei + EE;
    const int* ew      = (const int*)d_in[2];
    const int* batch   = (const int*)d_in[3];
    const void* mlp_w1 = d_in[4];
    const void* mlp_b1 = d_in[5];
    const void *bn1g = d_in[6], *bn1b = d_in[7], *bn1m = d_in[8], *bn1v = d_in[9];
    const void* mlp_w2 = d_in[10];
    const void* mlp_b2 = d_in[11];
    const void *bn2g = d_in[12], *bn2b = d_in[13], *bn2m = d_in[14], *bn2v = d_in[15];
    const void* g0w    = d_in[16];
    const void* g0as   = d_in[17];
    const void* g0ad   = d_in[18];
    const void* g0bias = d_in[19];
    const void* g1w    = d_in[20];
    const void* g1as   = d_in[21];
    const void* g1ad   = d_in[22];
    const void* g1bias = d_in[23];
    const void *bn3g = d_in[24], *bn3b = d_in[25], *bn3m = d_in[26], *bn3v = d_in[27];
    const void* fin_w1 = d_in[28];
    const void* fin_b1 = d_in[29];
    const void* fin_w2 = d_in[30];
    const void* fin_b2 = d_in[31];

    char* ws = (char*)d_ws;
    u16*  XB   = (u16*)(ws + OFF_XB);
    u16*  h1   = (u16*)(ws + OFF_H1);
    u16*  h2   = (u16*)(ws + OFF_H2);
    u16*  xw   = (u16*)(ws + OFF_XW);    // row-major [NN][512]
    u16*  h34  = (u16*)(ws + OFF_H34);   // row-major [NN][512]
    float* ls  = (float*)(ws + OFF_LS);
    float* ld  = (float*)(ws + OFF_LD);
    int*  deg  = (int*)(ws + OFF_DEG);
    int*  off  = (int*)(ws + OFF_OFFS);
    int*  cur  = (int*)(ws + OFF_CUR);
    u16*  csrc = (u16*)(ws + OFF_CSRC);
    int*  gcnt = (int*)(ws + OFF_GCNT);
    int*  goff = (int*)(ws + OFF_GOFF);
    int*  part = (int*)(ws + OFF_PART);
    int*  ptot = (int*)(ws + OFF_PTOT);
    float* S1 = (float*)(ws + OFF_ST);
    float* T1 = S1 + 256;
    float* S2 = T1 + 256;
    float* T2 = S2 + 256;
    float* S3 = T2 + 256;
    float* T3 = S3 + 512;
    u16* w1T = (u16*)(ws + OFF_W1T);
    u16* w2T = (u16*)(ws + OFF_W2T);
    u16* g0T = (u16*)(ws + OFF_G0T);
    u16* g1T = (u16*)(ws + OFF_G1T);
    unsigned* flag = (unsigned*)(ws + OFF_FLAG);
    u16* A0S = (u16*)(ws + OFF_A0S);
    u16* A0D = (u16*)(ws + OFF_A0D);
    u16* A1S = (u16*)(ws + OFF_A1S);
    u16* A1D = (u16*)(ws + OFF_A1D);
    float* GB0 = (float*)(ws + OFF_GB0);
    float* GB1 = (float*)(ws + OFF_GB1);
    float* FB1 = (float*)(ws + OFF_FB1);
    float* FB2 = (float*)(ws + OFF_FB2);
    float* PP = (float*)(ws + OFF_PP);            // pooling partials [NG][PSPL][C1]
    float2* PLS = (float2*)(ws + OFF_PLS);        // logits partials [4][NN]

    // dtype detection + input normalization (+ deg/gcnt init)
    detect_dtype<<<1, 256, 0, stream>>>((const u16*)x, (const u16*)mlp_w1, (const u16*)fin_w1, flag);
    cvt_x<<<(NN * FD / 4) / 256, 256, 0, stream>>>(flag, x, XB, deg, gcnt);
    prep_trans<<<121, 256, 0, stream>>>(flag,
                                        bn1g, bn1b, bn1m, bn1v, mlp_b1,
                                        bn2g, bn2b, bn2m, bn2v, mlp_b2,
                                        bn3g, bn3b, bn3m, bn3v,
                                        g0as, g0ad, g0bias, g1as, g1ad, g1bias,
                                        fin_b1, fin_b2,
                                        S1, T1, S2, T2, S3, T3,
                                        A0S, A0D, A1S, A1D, GB0, GB1, FB1, FB2,
                                        mlp_w1, mlp_w2, g0w, g1w, w1T, w2T, g0T, g1T);

    // CSR build (graph fixed across both layers) + graph offsets
    hist_k<<<HB, 256, 0, stream>>>(dst, ew, batch, deg, gcnt);
    scan_blk<<<NBLK, 256, 0, stream>>>(deg, off, part);
    scan_small<<<1, 128, 0, stream>>>(part, ptot, gcnt, goff);
    scan_add<<<NBLK, 256, 0, stream>>>(off, part, ptot, cur);
    csr_fill<<<HB, 256, 0, stream>>>(src, dst, ew, cur, csrc);

    // MLP (157 row-blocks of 128 cover 20096 >= 20000)
    gemm_tile<1><<<dim3(157, 2), 256, 0, stream>>>(XB, w1T, h1, S1, T1, nullptr, nullptr, nullptr, NN, C0, FD);
    gemm_tile<1><<<dim3(157, 2), 256, 0, stream>>>(h1, w2T, h2, S2, T2, nullptr, nullptr, nullptr, NN, C0, C0);

    // GAT layer 0 (logits fused into gemm epilogue; softmax fused into aggregation)
    gemm_tile<3><<<dim3(157, 4), 256, 0, stream>>>(h2, g0T, xw, nullptr, nullptr, A0S, A0D, PLS, NN, C1, C0);
    ls_combine<<<NBLK, 256, 0, stream>>>(PLS, ls, ld);
    gat_agg_fused<0><<<(NN / 2) / 4, 256, 0, stream>>>(off, csrc, ls, ld, xw, GB0, h34);
    gat_agg_fused<1><<<(NN / 2) / 4, 256, 0, stream>>>(off, csrc, ls, ld, xw, GB0, h34);

    // GAT layer 1
    gemm_tile<3><<<dim3(157, 4), 256, 0, stream>>>(h34, g1T, xw, nullptr, nullptr, A1S, A1D, PLS, NN, C1, C1);
    ls_combine<<<NBLK, 256, 0, stream>>>(PLS, ls, ld);
    gat_agg_fused<0><<<(NN / 2) / 4, 256, 0, stream>>>(off, csrc, ls, ld, xw, GB1, h34);
    gat_agg_fused<1><<<(NN / 2) / 4, 256, 0, stream>>>(off, csrc, ls, ld, xw, GB1, h34);

    // pool stage 1 + fused pool_fin/fc1/fc2
    pool_part<<<dim3(NG, PSPL), 128, 0, stream>>>(h34, goff, PP);
    head_all<<<NG, 512, 0, stream>>>(flag, PP, goff, S3, T3, fin_w1, FB1, fin_w2, FB2, d_out);
}